// Round 4
// baseline (38.974 us; speedup 1.0000x reference)
//
#include <hip/hip_runtime.h>
#include <hip/hip_bf16.h>
#include <math.h>
#include <float.h>

// Problem constants (setup_inputs: conv_out [1,512,20,31] f32, rois [n,5] f32)
#define CCH 512
#define HH 20
#define WW 31
#define HW (HH * WW)

// fl32(1/3) = 0x3EAAAAAB = 0.3333333432674408.
// XLA's algebraic simplifier rewrites `x / 3` (constant divisor) into
// `x * fl32(1/3)`. For roi dim == 7 this puts bin 1 ulp HIGH, so
// ceil(3*bin) = 8 (not 7): the last bin gains one extra row/column vs
// correctly-rounded division. We must reproduce that to match the JAX-
// computed expected output. (R1-R3 all failed identically at 0.816 with
// correctly-rounded division in both f32 and f64 — precision-independent,
// consistent only with this rewrite.)
#define RCP3 0.33333334f

// ---------------------------------------------------------------------------
// ROI max pool 3x3 + mean over bins. One block per ROI, one thread per channel.
// Direct [C,H,W] reads; feature map is 1.27MB -> L2-resident.
// ---------------------------------------------------------------------------
__global__ void roi_pool_avg_direct(const float* __restrict__ fm,
                                    const float* __restrict__ rois,
                                    float* __restrict__ out) {
    const int roi = blockIdx.x;
    const int c   = threadIdx.x;

    const float* r = rois + (size_t)roi * 5;
    const int bidx = (int)r[0];

    const float x1 = rintf(r[1] * 0.0625f);   // exact product; RNE round = jnp.round
    const float y1 = rintf(r[2] * 0.0625f);
    const float x2 = rintf(r[3] * 0.0625f);
    const float y2 = rintf(r[4] * 0.0625f);
    const float roi_w = fmaxf(x2 - x1 + 1.0f, 1.0f);   // small ints, exact
    const float roi_h = fmaxf(y2 - y1 + 1.0f, 1.0f);
    const float bin_w = roi_w * RCP3;   // mimic XLA div->rcp-mul rewrite
    const float bin_h = roi_h * RCP3;

    // Bin boundaries: floor/ceil of p*bin (f32), + integer origin, clip.
    int h0[3], h1[3], w0[3], w1[3];
#pragma unroll
    for (int p = 0; p < 3; ++p) {
        float hs = fminf(fmaxf(floorf((float)p * bin_h) + y1, 0.0f), 20.0f);
        float he = fminf(fmaxf(ceilf((float)(p + 1) * bin_h) + y1, 0.0f), 20.0f);
        h0[p] = (int)hs;
        h1[p] = (int)he;
        float ws = fminf(fmaxf(floorf((float)p * bin_w) + x1, 0.0f), 31.0f);
        float we = fminf(fmaxf(ceilf((float)(p + 1) * bin_w) + x1, 0.0f), 31.0f);
        w0[p] = (int)ws;
        w1[p] = (int)we;
    }

    const float* base = fm + ((size_t)bidx * CCH + c) * HW;  // this channel's plane

    float sum = 0.0f;
#pragma unroll
    for (int ph = 0; ph < 3; ++ph) {
#pragma unroll
        for (int pw = 0; pw < 3; ++pw) {
            const bool nonempty = (h0[ph] < h1[ph]) && (w0[pw] < w1[pw]);
            float mx = -FLT_MAX;
            for (int h = h0[ph]; h < h1[ph]; ++h) {
                for (int w = w0[pw]; w < w1[pw]; ++w) {
                    mx = fmaxf(mx, base[h * WW + w]);
                }
            }
            sum += nonempty ? mx : 0.0f;   // empty bin -> 0 (reference m.any() path)
        }
    }
    out[(size_t)roi * CCH + c] = sum / 9.0f;   // mean over the 9 bins
}

extern "C" void kernel_launch(void* const* d_in, const int* in_sizes, int n_in,
                              void* d_out, int out_size, void* d_ws, size_t ws_size,
                              hipStream_t stream) {
    const float* conv = (const float*)d_in[0];
    const float* rois = (const float*)d_in[1];
    float* out = (float*)d_out;
    const int n = in_sizes[1] / 5;            // 512 ROIs

    roi_pool_avg_direct<<<n, CCH, 0, stream>>>(conv, rois, out);
}

// Round 5
// 26.055 us; speedup vs baseline: 1.4959x; 1.4959x over previous
//
#include <hip/hip_runtime.h>
#include <hip/hip_bf16.h>
#include <math.h>
#include <float.h>

// Problem constants (setup_inputs: conv_out [1,512,20,31] f32, rois [n,5] f32)
#define CCH 512
#define HH 20
#define WW 31
#define HW (HH * WW)

// fl32(1/3) = 0x3EAAAAAB. XLA rewrites `x / 3` (constant divisor) into
// `x * fl32(1/3)`; for roi dim == 7 this lands 1 ulp high so ceil(3*bin)=8.
// Verified bit-exact vs the JAX/np reference in R4 (absmax 0.0). DO NOT
// replace with a true division — that was R1-R3's 0.816 failure.
#define RCP3 0.33333334f

// ---------------------------------------------------------------------------
// Shared bound computation (proven numerics, R4).
// ---------------------------------------------------------------------------
__device__ __forceinline__ void roi_bounds(const float* __restrict__ r,
                                           int* h0, int* h1, int* w0, int* w1,
                                           int& bidx) {
    bidx = (int)r[0];
    const float x1 = rintf(r[1] * 0.0625f);   // exact scale; RNE = jnp.round
    const float y1 = rintf(r[2] * 0.0625f);
    const float x2 = rintf(r[3] * 0.0625f);
    const float y2 = rintf(r[4] * 0.0625f);
    const float roi_w = fmaxf(x2 - x1 + 1.0f, 1.0f);
    const float roi_h = fmaxf(y2 - y1 + 1.0f, 1.0f);
    const float bin_w = roi_w * RCP3;         // XLA div->rcp-mul mimic
    const float bin_h = roi_h * RCP3;
#pragma unroll
    for (int p = 0; p < 3; ++p) {
        float hs = fminf(fmaxf(floorf((float)p * bin_h) + y1, 0.0f), 20.0f);
        float he = fminf(fmaxf(ceilf((float)(p + 1) * bin_h) + y1, 0.0f), 20.0f);
        h0[p] = (int)hs;
        h1[p] = (int)he;
        float ws = fminf(fmaxf(floorf((float)p * bin_w) + x1, 0.0f), 31.0f);
        float we = fminf(fmaxf(ceilf((float)(p + 1) * bin_w) + x1, 0.0f), 31.0f);
        w0[p] = (int)ws;
        w1[p] = (int)we;
    }
}

// ---------------------------------------------------------------------------
// Kernel 1: transpose [C,H,W] -> [H*W, C]. 1.27MB, L2-resident; writes
// coalesced, reads strided (cheap at this size).
// ---------------------------------------------------------------------------
__global__ void transpose_chw_hwc(const float* __restrict__ in,
                                  float* __restrict__ out) {
    int idx = blockIdx.x * blockDim.x + threadIdx.x;
    if (idx >= HW * CCH) return;
    int hw = idx >> 9;          // / 512
    int c  = idx & (CCH - 1);   // % 512
    out[idx] = in[c * HW + hw];
}

// ---------------------------------------------------------------------------
// Kernel 2: pool over [H*W, C] layout, float4-vectorized over channels.
// 1 block per ROI, 128 threads; thread t owns channels 4t..4t+3. A wave's
// 64 lanes read 64*16B = 1KiB contiguous per (h,w) -> fully coalesced.
// ---------------------------------------------------------------------------
__global__ void roi_pool_avg_t(const float* __restrict__ fm_t,
                               const float* __restrict__ rois,
                               float* __restrict__ out) {
    const int roi = blockIdx.x;
    const int t   = threadIdx.x;           // channel group: 4t..4t+3

    int h0[3], h1[3], w0[3], w1[3], bidx;
    roi_bounds(rois + (size_t)roi * 5, h0, h1, w0, w1, bidx);

    const float4* base = (const float4*)fm_t + (size_t)bidx * HW * (CCH / 4) + t;

    float4 sum = make_float4(0.f, 0.f, 0.f, 0.f);
#pragma unroll
    for (int ph = 0; ph < 3; ++ph) {
#pragma unroll
        for (int pw = 0; pw < 3; ++pw) {
            const bool nonempty = (h0[ph] < h1[ph]) && (w0[pw] < w1[pw]);
            float4 mx = make_float4(-FLT_MAX, -FLT_MAX, -FLT_MAX, -FLT_MAX);
            for (int h = h0[ph]; h < h1[ph]; ++h) {
                for (int w = w0[pw]; w < w1[pw]; ++w) {
                    const float4 v = base[(size_t)(h * WW + w) * (CCH / 4)];
                    mx.x = fmaxf(mx.x, v.x);
                    mx.y = fmaxf(mx.y, v.y);
                    mx.z = fmaxf(mx.z, v.z);
                    mx.w = fmaxf(mx.w, v.w);
                }
            }
            if (nonempty) {
                sum.x += mx.x; sum.y += mx.y; sum.z += mx.z; sum.w += mx.w;
            }
        }
    }
    sum.x /= 9.0f; sum.y /= 9.0f; sum.z /= 9.0f; sum.w /= 9.0f;
    ((float4*)out)[(size_t)roi * (CCH / 4) + t] = sum;
}

// ---------------------------------------------------------------------------
// Fallback: direct [C,H,W] kernel (R4's verified-passing version), used only
// if ws_size can't hold the transposed map.
// ---------------------------------------------------------------------------
__global__ void roi_pool_avg_direct(const float* __restrict__ fm,
                                    const float* __restrict__ rois,
                                    float* __restrict__ out) {
    const int roi = blockIdx.x;
    const int c   = threadIdx.x;

    int h0[3], h1[3], w0[3], w1[3], bidx;
    roi_bounds(rois + (size_t)roi * 5, h0, h1, w0, w1, bidx);

    const float* base = fm + ((size_t)bidx * CCH + c) * HW;

    float sum = 0.0f;
#pragma unroll
    for (int ph = 0; ph < 3; ++ph) {
#pragma unroll
        for (int pw = 0; pw < 3; ++pw) {
            const bool nonempty = (h0[ph] < h1[ph]) && (w0[pw] < w1[pw]);
            float mx = -FLT_MAX;
            for (int h = h0[ph]; h < h1[ph]; ++h)
                for (int w = w0[pw]; w < w1[pw]; ++w)
                    mx = fmaxf(mx, base[h * WW + w]);
            sum += nonempty ? mx : 0.0f;
        }
    }
    out[(size_t)roi * CCH + c] = sum / 9.0f;
}

extern "C" void kernel_launch(void* const* d_in, const int* in_sizes, int n_in,
                              void* d_out, int out_size, void* d_ws, size_t ws_size,
                              hipStream_t stream) {
    const float* conv = (const float*)d_in[0];
    const float* rois = (const float*)d_in[1];
    float* out = (float*)d_out;
    const int n = in_sizes[1] / 5;            // 512 ROIs

    const size_t trans_bytes = (size_t)HW * CCH * sizeof(float);
    if (ws_size >= trans_bytes) {
        float* fm_t = (float*)d_ws;
        const int total = HW * CCH;           // 317440
        transpose_chw_hwc<<<(total + 255) / 256, 256, 0, stream>>>(conv, fm_t);
        roi_pool_avg_t<<<n, CCH / 4, 0, stream>>>(fm_t, rois, out);
    } else {
        roi_pool_avg_direct<<<n, CCH, 0, stream>>>(conv, rois, out);
    }
}

// Round 6
// 22.036 us; speedup vs baseline: 1.7687x; 1.1824x over previous
//
#include <hip/hip_runtime.h>
#include <hip/hip_bf16.h>
#include <math.h>
#include <float.h>

// Problem constants (setup_inputs: conv_out [1,512,20,31] f32, rois [n,5] f32)
#define CCH 512
#define HH 20
#define WW 31
#define HW (HH * WW)          // 620

// fl32(1/3) = 0x3EAAAAAB. XLA rewrites `x / 3` (constant divisor) into
// `x * fl32(1/3)`; for roi dim == 7 this lands 1 ulp high so ceil(3*bin)=8.
// Verified bit-exact vs the JAX/np reference (R4/R5, absmax 0.0). DO NOT
// replace with a true division — that was R1-R3's 0.816 failure.
#define RCP3 0.33333334f

#define CG 16                 // channels per block
#define RG 32                 // rois per block

// ---------------------------------------------------------------------------
// Proven bound computation (R4).
// ---------------------------------------------------------------------------
__device__ __forceinline__ void roi_bounds(const float* __restrict__ r,
                                           int* h0, int* h1, int* w0, int* w1) {
    const float x1 = rintf(r[1] * 0.0625f);   // exact scale; RNE = jnp.round
    const float y1 = rintf(r[2] * 0.0625f);
    const float x2 = rintf(r[3] * 0.0625f);
    const float y2 = rintf(r[4] * 0.0625f);
    const float roi_w = fmaxf(x2 - x1 + 1.0f, 1.0f);
    const float roi_h = fmaxf(y2 - y1 + 1.0f, 1.0f);
    const float bin_w = roi_w * RCP3;         // XLA div->rcp-mul mimic
    const float bin_h = roi_h * RCP3;
#pragma unroll
    for (int p = 0; p < 3; ++p) {
        float hs = fminf(fmaxf(floorf((float)p * bin_h) + y1, 0.0f), 20.0f);
        float he = fminf(fmaxf(ceilf((float)(p + 1) * bin_h) + y1, 0.0f), 20.0f);
        h0[p] = (int)hs;
        h1[p] = (int)he;
        float ws = fminf(fmaxf(floorf((float)p * bin_w) + x1, 0.0f), 31.0f);
        float we = fminf(fmaxf(ceilf((float)(p + 1) * bin_w) + x1, 0.0f), 31.0f);
        w0[p] = (int)ws;
        w1[p] = (int)we;
    }
}

// ---------------------------------------------------------------------------
// Fused kernel (B==1 fast path). Block = (CG channels, RG rois).
//  - Staging: channels c0..c0+CG are CONTIGUOUS in native [C,H,W] layout ->
//    straight float4 memcpy into LDS, fully coalesced (fixes R5's transpose
//    scatter-read, which cost ~15us).
//  - Pooling: per-lane "strided" access moves to LDS where stride 620 gives
//    bank-step 12, <=2-way conflicts in a 16-lane subgroup (free, m136).
//  - Writes: lane = channel-within-group -> 64B contiguous segments.
// ---------------------------------------------------------------------------
__global__ __launch_bounds__(256)
void roi_pool_fused(const float* __restrict__ fm,
                    const float* __restrict__ rois,
                    float* __restrict__ out, int n) {
    __shared__ float plane[CG * HW];                  // 39680 B, c-major
    __shared__ int sb_h0[3][RG], sb_h1[3][RG], sb_w0[3][RG], sb_w1[3][RG];

    const int c0   = blockIdx.x * CG;
    const int roi0 = blockIdx.y * RG;
    const int t    = threadIdx.x;

    // Phase 1a: contiguous copy fm[c0*HW .. (c0+CG)*HW) -> LDS (float4).
    {
        const float4* src = (const float4*)(fm + (size_t)c0 * HW);
        float4* dst = (float4*)plane;
        for (int i = t; i < CG * (HW / 4); i += 256)  // 2480 float4s
            dst[i] = src[i];
    }
    // Phase 1b: bounds for this block's RG rois (threads 0..RG-1).
    if (t < RG) {
        const int roi = roi0 + t;
        if (roi < n) {
            int h0[3], h1[3], w0[3], w1[3];
            roi_bounds(rois + (size_t)roi * 5, h0, h1, w0, w1);
#pragma unroll
            for (int p = 0; p < 3; ++p) {
                sb_h0[p][t] = h0[p]; sb_h1[p][t] = h1[p];
                sb_w0[p][t] = w0[p]; sb_w1[p][t] = w1[p];
            }
        }
    }
    __syncthreads();

    // Phase 2: 256 threads = 16 rois x 16 channels per pass, 2 passes.
    const int c_local = t & (CG - 1);
    const int rsub0   = t >> 4;                       // 0..15
    const float* pl = plane + c_local * HW;
#pragma unroll
    for (int rr = 0; rr < RG / 16; ++rr) {
        const int rsub = rsub0 + rr * 16;
        const int roi  = roi0 + rsub;
        if (roi >= n) continue;
        float sum = 0.0f;
#pragma unroll
        for (int ph = 0; ph < 3; ++ph) {
            const int h0 = sb_h0[ph][rsub], h1 = sb_h1[ph][rsub];  // LDS broadcast
#pragma unroll
            for (int pw = 0; pw < 3; ++pw) {
                const int w0 = sb_w0[pw][rsub], w1 = sb_w1[pw][rsub];
                const bool nonempty = (h0 < h1) && (w0 < w1);
                float mx = -FLT_MAX;
                for (int h = h0; h < h1; ++h)
                    for (int w = w0; w < w1; ++w)
                        mx = fmaxf(mx, pl[h * WW + w]);
                sum += nonempty ? mx : 0.0f;          // empty bin -> 0
            }
        }
        out[(size_t)roi * CCH + c0 + c_local] = sum / 9.0f;
    }
}

// ---------------------------------------------------------------------------
// Fallback (any batch size): R4's verified direct kernel.
// ---------------------------------------------------------------------------
__global__ void roi_pool_avg_direct(const float* __restrict__ fm,
                                    const float* __restrict__ rois,
                                    float* __restrict__ out) {
    const int roi = blockIdx.x;
    const int c   = threadIdx.x;
    const float* r = rois + (size_t)roi * 5;
    const int bidx = (int)r[0];

    int h0[3], h1[3], w0[3], w1[3];
    roi_bounds(r, h0, h1, w0, w1);

    const float* base = fm + ((size_t)bidx * CCH + c) * HW;
    float sum = 0.0f;
#pragma unroll
    for (int ph = 0; ph < 3; ++ph)
#pragma unroll
        for (int pw = 0; pw < 3; ++pw) {
            const bool nonempty = (h0[ph] < h1[ph]) && (w0[pw] < w1[pw]);
            float mx = -FLT_MAX;
            for (int h = h0[ph]; h < h1[ph]; ++h)
                for (int w = w0[pw]; w < w1[pw]; ++w)
                    mx = fmaxf(mx, base[h * WW + w]);
            sum += nonempty ? mx : 0.0f;
        }
    out[(size_t)roi * CCH + c] = sum / 9.0f;
}

extern "C" void kernel_launch(void* const* d_in, const int* in_sizes, int n_in,
                              void* d_out, int out_size, void* d_ws, size_t ws_size,
                              hipStream_t stream) {
    const float* conv = (const float*)d_in[0];
    const float* rois = (const float*)d_in[1];
    float* out = (float*)d_out;
    const int n = in_sizes[1] / 5;                    // 512 ROIs
    const int B = in_sizes[0] / (CCH * HW);           // 1 for this problem

    if (B == 1) {
        dim3 grid(CCH / CG, (n + RG - 1) / RG);       // 32 x 16 = 512 blocks
        roi_pool_fused<<<grid, 256, 0, stream>>>(conv, rois, out, n);
    } else {
        roi_pool_avg_direct<<<n, CCH, 0, stream>>>(conv, rois, out);
    }
}